// Round 17
// baseline (141.153 us; speedup 1.0000x reference)
//
#include <hip/hip_runtime.h>
#include <math.h>

typedef float  f32x4  __attribute__((ext_vector_type(4)));
typedef __bf16 bf16x8 __attribute__((ext_vector_type(8)));
typedef __bf16 bf16x4 __attribute__((ext_vector_type(4)));

#define MFMA16(a, b, c) __builtin_amdgcn_mfma_f32_16x16x32_bf16((a), (b), (c), 0, 0, 0)

// tr-read: 64-bit LDS transpose read (4 bf16), literal offset
#define TRR(dst, a, lit)  asm volatile("ds_read_b64_tr_b16 %0, %1 offset:" lit : "=v"(dst) : "v"(a))
#define TRRM(dst, a, lit) asm volatile("ds_read_b64_tr_b16 %0, %1 offset:" lit : "=v"(dst) : "v"(a) : "memory")
#define SHUF8(a, b) __builtin_shufflevector((a), (b), 0, 1, 2, 3, 4, 5, 6, 7)

typedef __attribute__((address_space(3))) unsigned int lds_u32;
typedef __attribute__((address_space(1))) const unsigned int glb_u32;

__device__ __forceinline__ void gload16(const __bf16* g, char* l) {
    __builtin_amdgcn_global_load_lds((glb_u32*)g, (lds_u32*)l, 16, 0, 0);
}

// problem sizes
static constexpr int BATCH = 4;
static constexpr int CH    = 256;
static constexpr int M_TOT = BATCH * 4096;  // 16384

// qkv softmax pre-scale folded into Q: 0.125 * log2(e)
static constexpr float QSCALE = 0.18033688011112042f;

// workspace layout (bytes, 16-aligned)
static constexpr size_t OFF_WQKV  = 0;                              // 196608 bf16
static constexpr size_t OFF_WOUT  = 196608ull * 2;                  // 65536 bf16
static constexpr size_t OFF_STATS = OFF_WOUT + 65536ull * 2;        // 128 float2
static constexpr size_t OFF_HID   = OFF_STATS + 1024;               // hid / attn_out bf16
static constexpr size_t OFF_Q     = OFF_HID + (size_t)M_TOT * CH * 2;
static constexpr size_t OFF_K     = OFF_Q   + (size_t)M_TOT * CH * 2;   // kf fragment-major
static constexpr size_t OFF_V     = OFF_K   + (size_t)M_TOT * CH * 2;

// ---------------------------------------------------------------------------
// 1) fused: GN stats (blocks 0..127) + weight convert/permute (blocks 128..1151)
// ---------------------------------------------------------------------------
__global__ __launch_bounds__(256) void pre_kernel(const float* __restrict__ x,
                                                  float2* __restrict__ stats,
                                                  const float* __restrict__ wq,
                                                  const float* __restrict__ wo,
                                                  __bf16* __restrict__ wqf,
                                                  __bf16* __restrict__ wof) {
    if (blockIdx.x < 128) {
        int bg = blockIdx.x;  // 0..127
        const float4* p = (const float4*)(x + (size_t)bg * 32768);
        float s = 0.f, ss = 0.f;
        for (int i = threadIdx.x; i < 8192; i += 256) {
            float4 v = p[i];
            s  += (v.x + v.y) + (v.z + v.w);
            ss += v.x * v.x + v.y * v.y + v.z * v.z + v.w * v.w;
        }
#pragma unroll
        for (int d = 32; d > 0; d >>= 1) { s += __shfl_down(s, d); ss += __shfl_down(ss, d); }
        __shared__ float sh[8];
        int w = threadIdx.x >> 6, l = threadIdx.x & 63;
        if (l == 0) { sh[w] = s; sh[4 + w] = ss; }
        __syncthreads();
        if (threadIdx.x == 0) {
            float S = sh[0] + sh[1] + sh[2] + sh[3];
            float SS = sh[4] + sh[5] + sh[6] + sh[7];
            float mean = S * (1.f / 32768.f);
            float var  = SS * (1.f / 32768.f) - mean * mean;
            stats[bg] = make_float2(mean, rsqrtf(var + 1e-5f));
        }
    } else {
        int i = (blockIdx.x - 128) * 256 + threadIdx.x;   // 0 .. 262143
        if (i < 196608) {
            int e = i & 7, l = (i >> 3) & 63, kk = (i >> 9) & 7, jt = i >> 12;  // jt 0..47
            int kidx = kk * 32 + ((l >> 4) << 3) + e;
            int n = jt * 16 + (l & 15);
            wqf[i] = (__bf16)wq[kidx * 768 + n];
        } else {
            int i2 = i - 196608;                  // 0 .. 65535
            int e = i2 & 7, l = (i2 >> 3) & 63, kk = (i2 >> 9) & 7, jt = i2 >> 12;  // jt 0..15
            int kidx = kk * 32 + ((l >> 4) << 3) + e;
            int n = jt * 16 + (l & 15);
            wof[i2] = (__bf16)wo[kidx * 256 + n];
        }
    }
}

// ---------------------------------------------------------------------------
// 2) GN apply + transpose: hid[b][n][c] = gn(x)[b][c][n]  (bf16)
// ---------------------------------------------------------------------------
__global__ __launch_bounds__(256) void gn_apply(const float* __restrict__ x,
                                                const float* __restrict__ gamma,
                                                const float* __restrict__ beta,
                                                const float2* __restrict__ stats,
                                                __bf16* __restrict__ hid) {
    int b  = blockIdx.x >> 6;
    int n0 = (blockIdx.x & 63) << 6;
    int c  = threadIdx.x;
    float2 st = stats[b * 32 + (c >> 3)];
    float gm = gamma[c] * st.y;
    float bt = beta[c] - st.x * gm;
    const float* xp = x + ((size_t)(b * 256 + c)) * 4096 + n0;
    __bf16* hp = hid + ((size_t)(b * 4096 + n0)) * 256 + c;
#pragma unroll
    for (int j4 = 0; j4 < 16; ++j4) {
        float4 v = *(const float4*)(xp + j4 * 4);
        hp[(size_t)(j4 * 4 + 0) * 256] = (__bf16)(v.x * gm + bt);
        hp[(size_t)(j4 * 4 + 1) * 256] = (__bf16)(v.y * gm + bt);
        hp[(size_t)(j4 * 4 + 2) * 256] = (__bf16)(v.z * gm + bt);
        hp[(size_t)(j4 * 4 + 3) * 256] = (__bf16)(v.w * gm + bt);
    }
}

// ---------------------------------------------------------------------------
// 3) QKV GEMM: [16384,256] x [256,768] + bias.
//    q,v -> [B,H,4096,64] row-major;  k -> FRAGMENT-MAJOR global layout
//      kf[((bh*64 + t)*8 + f)*512 + lane*8 + e] =
//        K[key = t*64 + (f&3)*16 + (lane&15)][d = (f>>2)*32 + ((lane>>4)&3)*8 + e]
//    (attn reads frags as coalesced 1KB global loads straight to VGPR).
//    Q pre-scaled by 0.125*log2(e).
// ---------------------------------------------------------------------------
__global__ __launch_bounds__(256) void qkv_gemm(const __bf16* __restrict__ hid,
                                                const __bf16* __restrict__ wf,
                                                const float* __restrict__ bqkv,
                                                __bf16* __restrict__ qb,
                                                __bf16* __restrict__ kf,
                                                __bf16* __restrict__ vb) {
    const int mt = blockIdx.x, nt = blockIdx.y;
    const int tid = threadIdx.x;
    const int w = tid >> 6, l = tid & 63;
    const int lr = l & 15, lh = l >> 4;
    f32x4 acc[4] = {{0.f,0.f,0.f,0.f},{0.f,0.f,0.f,0.f},{0.f,0.f,0.f,0.f},{0.f,0.f,0.f,0.f}};
    const __bf16* ap = hid + (size_t)(mt * 64 + w * 16 + lr) * 256 + lh * 8;
#pragma unroll
    for (int kk = 0; kk < 8; ++kk) {
        bf16x8 a = *(const bf16x8*)(ap + kk * 32);
#pragma unroll
        for (int fj = 0; fj < 4; ++fj) {
            bf16x8 bf = *(const bf16x8*)(wf + (size_t)(((nt * 4 + fj) * 8 + kk) * 64 + l) * 8);
            acc[fj] = MFMA16(a, bf, acc[fj]);
        }
    }
    const int part = nt % 3;           // 0=q 1=k 2=v (uniform per block)
    const int head = nt / 3;
    const int b  = mt >> 6;
    const int n0 = (mt & 63) * 64;

    if (part == 1) {
        // K: route through LDS transpose, emit fragment-major global layout
        __shared__ float tile[64][72];
#pragma unroll
        for (int fj = 0; fj < 4; ++fj) {
            float bias = bqkv[head * 192 + 64 + fj * 16 + lr];
#pragma unroll
            for (int r = 0; r < 4; ++r)
                tile[w * 16 + lh * 4 + r][fj * 16 + lr] = acc[fj][r] + bias;
        }
        __syncthreads();
        const int f = tid >> 5;              // 0..7
        const int fj2 = f & 3, half = f >> 2;
        const int la0 = tid & 31;
        __bf16* kdst = kf + (((size_t)((b * 4 + head) * 64 + (mt & 63)) * 8 + f) * 512);
#pragma unroll
        for (int s = 0; s < 2; ++s) {
            int la = la0 + s * 32;
            const float* src = &tile[fj2 * 16 + (la & 15)][half * 32 + ((la >> 4) & 3) * 8];
            bf16x8 w8;
#pragma unroll
            for (int e = 0; e < 8; ++e) w8[e] = (__bf16)src[e];
            *(bf16x8*)(kdst + la * 8) = w8;
        }
    } else {
        __bf16* dst = (part == 0) ? qb : vb;
        const float sc = (part == 0) ? QSCALE : 1.0f;
        int mbase = w * 16 + lh * 4;
#pragma unroll
        for (int fj = 0; fj < 4; ++fj) {
            int dd = fj * 16 + lr;
            float bias = bqkv[head * 192 + part * 64 + dd];
#pragma unroll
            for (int r = 0; r < 4; ++r) {
                int n = n0 + mbase + r;
                dst[((size_t)((b * 4 + head) * 4096 + n)) * 64 + dd] = (__bf16)((acc[fj][r] + bias) * sc);
            }
        }
    }
}

// ---------------------------------------------------------------------------
// 4) Flash attention, swapped-operand, STATIC softmax, x32 PV, 2 q-subtiles.
//    K: NO LDS — fragment-major global loads straight to VGPR, register
//    double-buffer prefetched 1 tile ahead (L2-resident: 1MB/XCD).
//    V: pi-keyed LDS dbuf (16KB) + tr-reads, as before.
//    Grid 512, XCD swizzle, 4 waves x (16 q-rows x 2 subtiles).
// ---------------------------------------------------------------------------
__global__ __launch_bounds__(256, 2) void attn_fwd(const __bf16* __restrict__ q,
                                                   const __bf16* __restrict__ kf,
                                                   const __bf16* __restrict__ v,
                                                   __bf16* __restrict__ ao) {
    const int id = blockIdx.x;
    const int within = id >> 3;                       // 0..63
    const int bh = ((id & 7) << 1) + (within >> 5);   // XCD (id&7) owns bh pair
    const int q0 = (within & 31) * 128;
    const int tid = threadIdx.x;
    const int wv = tid >> 6, l = tid & 63;
    const int lr = l & 15, lh = l >> 4;

    __shared__ __attribute__((aligned(16))) char smem[16384];  // V dbuf 2x8KB

    const size_t base = (size_t)bh * (4096 * 64);

    // ---- V staging addresses (pi-keyed; chunk c = wv*64 + l, and +256) ----
    const int c0 = wv * 64 + l;
    const int dt0 = c0 >> 7, kq0 = (c0 >> 3) & 15, klo0 = (l >> 1) & 3, d80 = l & 1;
    const int gv0 = (kq0 * 4 + klo0) * 64 + dt0 * 16 + d80 * 8;
    const int gv1 = gv0 + 32;                               // dt+2
    const int lw0 = wv * 1024;                              // wave-uniform LDS bases
    const int lw1 = 4096 + wv * 1024;

    const __bf16* vg = v + base;
    const __bf16* kl = kf + (size_t)bh * (64 * 4096) + l * 8;   // per-lane frag base

    // per-lane tr-read base for V slot 0
    const unsigned vAbase = (unsigned)(size_t)smem + (unsigned)(lr * 2 + lh * 128);

    // Q fragments for both subtiles (B-operand of swapped QK^T; pre-scaled)
    bf16x8 qf0a, qf1a, qf0b, qf1b;
    {
        const __bf16* qp = q + base + (size_t)(q0 + wv * 16 + lr) * 64 + lh * 8;
        qf0a = *(const bf16x8*)qp;
        qf1a = *(const bf16x8*)(qp + 32);
        qf0b = *(const bf16x8*)(qp + 4096);        // +64 rows
        qf1b = *(const bf16x8*)(qp + 4096 + 32);
    }
    bf16x8 ones;
#pragma unroll
    for (int e = 0; e < 8; ++e) ones[e] = (__bf16)1.0f;

    f32x4 oa[4] = {{0.f,0.f,0.f,0.f},{0.f,0.f,0.f,0.f},{0.f,0.f,0.f,0.f},{0.f,0.f,0.f,0.f}};
    f32x4 ob[4] = {{0.f,0.f,0.f,0.f},{0.f,0.f,0.f,0.f},{0.f,0.f,0.f,0.f},{0.f,0.f,0.f,0.f}};
    f32x4 o4a = {0.f, 0.f, 0.f, 0.f};
    f32x4 o4b = {0.f, 0.f, 0.f, 0.f};

    // prologue: V tile 0 -> slot 0; K tile 0 -> kA registers
    gload16(vg + gv0, smem + lw0);
    gload16(vg + gv1, smem + lw1);
    bf16x8 kA[8], kB[8];
#pragma unroll
    for (int i = 0; i < 8; ++i) kA[i] = *(const bf16x8*)(kl + i * 512);
    __syncthreads();

    auto body = [&](unsigned slot, bf16x8 (&kcur)[8], bf16x8 (&knext)[8], int tnext) {
        // stage V(t+1) into other slot; prefetch K(t+1) into knext regs
        if (tnext < 64) {
            const __bf16* vp = vg + (size_t)tnext * 4096;
            char* vd = smem + (slot ^ 8192u);
            gload16(vp + gv0, vd + lw0);
            gload16(vp + gv1, vd + lw1);
            const __bf16* kp = kl + (size_t)tnext * 4096;
#pragma unroll
            for (int i = 0; i < 8; ++i) knext[i] = *(const bf16x8*)(kp + i * 512);
        }

        // ---- S^T = K Q^T (pure register operands) ----
        f32x4 sa[4], sb[4];
        const f32x4 z = {0.f, 0.f, 0.f, 0.f};
        __builtin_amdgcn_s_setprio(1);
#pragma unroll
        for (int fj = 0; fj < 4; ++fj) {
            sa[fj] = MFMA16(kcur[fj], qf0a, z);
            sb[fj] = MFMA16(kcur[fj], qf0b, z);
            sa[fj] = MFMA16(kcur[4 + fj], qf1a, sa[fj]);
            sb[fj] = MFMA16(kcur[4 + fj], qf1b, sb[fj]);
        }
        __builtin_amdgcn_s_setprio(0);

        // ---- issue ALL 16 V tr-reads; latency hides under exp2 ----
        const unsigned vA = vAbase + slot;
        bf16x4 u0, u1, u2, u3, u4, u5, u6, u7, u8, u9, u10, u11, u12, u13, u14, u15;
        TRRM(u0,  vA, "0");    TRR(u1,  vA, "512");
        TRR(u2,  vA, "1024");  TRR(u3,  vA, "1536");
        TRR(u4,  vA, "2048");  TRR(u5,  vA, "2560");
        TRR(u6,  vA, "3072");  TRR(u7,  vA, "3584");
        TRR(u8,  vA, "4096");  TRR(u9,  vA, "4608");
        TRR(u10, vA, "5120");  TRR(u11, vA, "5632");
        TRR(u12, vA, "6144");  TRR(u13, vA, "6656");
        TRR(u14, vA, "7168");  TRR(u15, vA, "7680");

        // ---- static softmax: p = exp2(s) -> PV B-fragments (in register) ----
        bf16x8 Ba0, Ba1, Bb0, Bb1;
#pragma unroll
        for (int fj = 0; fj < 4; ++fj)
#pragma unroll
            for (int r = 0; r < 4; ++r) {
                float pa = __builtin_amdgcn_exp2f(sa[fj][r]);
                float pb = __builtin_amdgcn_exp2f(sb[fj][r]);
                if (fj < 2) { Ba0[fj * 4 + r] = (__bf16)pa; Bb0[fj * 4 + r] = (__bf16)pb; }
                else        { Ba1[(fj - 2) * 4 + r] = (__bf16)pa; Bb1[(fj - 2) * 4 + r] = (__bf16)pb; }
            }

        // ---- single wait + one 20-MFMA cluster (V frags shared) ----
        asm volatile("s_waitcnt lgkmcnt(0)" ::: "memory");
        __builtin_amdgcn_sched_barrier(0);
        __builtin_amdgcn_s_setprio(1);
        bf16x8 v01 = SHUF8(u0,  u1),  v23 = SHUF8(u2,  u3);
        bf16x8 v45 = SHUF8(u4,  u5),  v67 = SHUF8(u6,  u7);
        oa[0] = MFMA16(v01, Ba0, oa[0]);  ob[0] = MFMA16(v01, Bb0, ob[0]);
        oa[1] = MFMA16(v45, Ba0, oa[1]);  ob[1] = MFMA16(v45, Bb0, ob[1]);
        oa[0] = MFMA16(v23, Ba1, oa[0]);  ob[0] = MFMA16(v23, Bb1, ob[0]);
        oa[1] = MFMA16(v67, Ba1, oa[1]);  ob[1] = MFMA16(v67, Bb1, ob[1]);
        o4a   = MFMA16(ones, Ba0, o4a);   o4b   = MFMA16(ones, Bb0, o4b);
        bf16x8 v89 = SHUF8(u8,  u9),  vab = SHUF8(u10, u11);
        bf16x8 vcd = SHUF8(u12, u13), vef = SHUF8(u14, u15);
        oa[2] = MFMA16(v89, Ba0, oa[2]);  ob[2] = MFMA16(v89, Bb0, ob[2]);
        oa[3] = MFMA16(vcd, Ba0, oa[3]);  ob[3] = MFMA16(vcd, Bb0, ob[3]);
        oa[2] = MFMA16(vab, Ba1, oa[2]);  ob[2] = MFMA16(vab, Bb1, ob[2]);
        oa[3] = MFMA16(vef, Ba1, oa[3]);  ob[3] = MFMA16(vef, Bb1, ob[3]);
        o4a   = MFMA16(ones, Ba1, o4a);   o4b   = MFMA16(ones, Bb1, o4b);
        __builtin_amdgcn_s_setprio(0);

        __syncthreads();   // V staging landed; slot flip safe
    };

    for (int t = 0; t < 64; t += 2) {
        body(0u,    kA, kB, t + 1);
        body(8192u, kB, kA, t + 2);
    }

    // epilogue: every lane holds the full denominators in o4a[0]/o4b[0]
    float inva = 1.0f / o4a[0];
    float invb = 1.0f / o4b[0];
    int b = bh >> 2, h = bh & 3;
    int n = q0 + wv * 16 + lr;
    __bf16* dsta = ao + ((size_t)(b * 4096 + n)) * 256 + h * 64 + lh * 4;
    __bf16* dstb = dsta + 64 * 256;
#pragma unroll
    for (int fd = 0; fd < 4; ++fd) {
        bf16x4 pka, pkb;
#pragma unroll
        for (int r = 0; r < 4; ++r) {
            pka[r] = (__bf16)(oa[fd][r] * inva);
            pkb[r] = (__bf16)(ob[fd][r] * invb);
        }
        *(bf16x4*)(dsta + fd * 16) = pka;
        *(bf16x4*)(dstb + fd * 16) = pkb;
    }
}

// ---------------------------------------------------------------------------
// 5) out projection + bias + residual + 1/sqrt(2), transposed store [B,C,N]
// ---------------------------------------------------------------------------
__global__ __launch_bounds__(256) void out_gemm(const __bf16* __restrict__ ao,
                                                const __bf16* __restrict__ wf,
                                                const float* __restrict__ bout,
                                                const float* __restrict__ x,
                                                float* __restrict__ out) {
    const int mt = blockIdx.x, nt = blockIdx.y;
    const int tid = threadIdx.x;
    const int w = tid >> 6, l = tid & 63;
    const int lr = l & 15, lh = l >> 4;
    f32x4 acc[4] = {{0.f,0.f,0.f,0.f},{0.f,0.f,0.f,0.f},{0.f,0.f,0.f,0.f},{0.f,0.f,0.f,0.f}};
    const __bf16* ap = ao + (size_t)(mt * 64 + w * 16 + lr) * 256 + lh * 8;
#pragma unroll
    for (int kk = 0; kk < 8; ++kk) {
        bf16x8 a = *(const bf16x8*)(ap + kk * 32);
#pragma unroll
        for (int fj = 0; fj < 4; ++fj) {
            bf16x8 bf = *(const bf16x8*)(wf + (size_t)(((nt * 4 + fj) * 8 + kk) * 64 + l) * 8);
            acc[fj] = MFMA16(a, bf, acc[fj]);
        }
    }
    __shared__ float tile[64][72];
#pragma unroll
    for (int fj = 0; fj < 4; ++fj) {
        float bias = bout[nt * 64 + fj * 16 + lr];
#pragma unroll
        for (int r = 0; r < 4; ++r)
            tile[w * 16 + lh * 4 + r][fj * 16 + lr] = acc[fj][r] + bias;
    }
    __syncthreads();
    int b  = mt >> 6;
    int n0 = (mt & 63) * 64;
    int c0 = nt * 64;
    int cl = tid >> 2, nq = tid & 3;
    size_t gbase = ((size_t)(b * 256 + c0 + cl)) * 4096 + n0 + nq * 16;
#pragma unroll
    for (int i = 0; i < 16; i += 4) {
        float4 xv = *(const float4*)(x + gbase + i);
        float4 ov;
        ov.x = (tile[nq * 16 + i + 0][cl] + xv.x) * 0.70710678118654752f;
        ov.y = (tile[nq * 16 + i + 1][cl] + xv.y) * 0.70710678118654752f;
        ov.z = (tile[nq * 16 + i + 2][cl] + xv.z) * 0.70710678118654752f;
        ov.w = (tile[nq * 16 + i + 3][cl] + xv.w) * 0.70710678118654752f;
        *(float4*)(out + gbase + i) = ov;
    }
}

// ---------------------------------------------------------------------------
extern "C" void kernel_launch(void* const* d_in, const int* in_sizes, int n_in,
                              void* d_out, int out_size, void* d_ws, size_t ws_size,
                              hipStream_t stream) {
    const float* x     = (const float*)d_in[0];
    const float* gamma = (const float*)d_in[1];
    const float* beta  = (const float*)d_in[2];
    const float* W_qkv = (const float*)d_in[3];
    const float* b_qkv = (const float*)d_in[4];
    const float* W_out = (const float*)d_in[5];
    const float* b_out = (const float*)d_in[6];
    float* out = (float*)d_out;
    char* ws = (char*)d_ws;

    __bf16* wqf   = (__bf16*)(ws + OFF_WQKV);
    __bf16* wof   = (__bf16*)(ws + OFF_WOUT);
    float2* stats = (float2*)(ws + OFF_STATS);
    __bf16* hid   = (__bf16*)(ws + OFF_HID);   // hid, then attn_out
    __bf16* qb    = (__bf16*)(ws + OFF_Q);
    __bf16* kfb   = (__bf16*)(ws + OFF_K);     // K fragment-major
    __bf16* vb    = (__bf16*)(ws + OFF_V);

    pre_kernel<<<1152, 256, 0, stream>>>(x, stats, W_qkv, W_out, wqf, wof);
    gn_apply<<<256, 256, 0, stream>>>(x, gamma, beta, stats, hid);
    qkv_gemm<<<dim3(256, 12), 256, 0, stream>>>(hid, wqf, b_qkv, qb, kfb, vb);
    attn_fwd<<<512, 256, 0, stream>>>(qb, kfb, vb, hid);
    out_gemm<<<dim3(256, 4), 256, 0, stream>>>(hid, wof, b_out, x, out);
}

// Round 18
// 134.693 us; speedup vs baseline: 1.0480x; 1.0480x over previous
//
#include <hip/hip_runtime.h>
#include <math.h>

typedef float  f32x4  __attribute__((ext_vector_type(4)));
typedef __bf16 bf16x8 __attribute__((ext_vector_type(8)));
typedef __bf16 bf16x4 __attribute__((ext_vector_type(4)));

#define MFMA16(a, b, c) __builtin_amdgcn_mfma_f32_16x16x32_bf16((a), (b), (c), 0, 0, 0)

// tr-read: 64-bit LDS transpose read (4 bf16), literal offset
#define TRR(dst, a, lit)  asm volatile("ds_read_b64_tr_b16 %0, %1 offset:" lit : "=v"(dst) : "v"(a))
#define TRRM(dst, a, lit) asm volatile("ds_read_b64_tr_b16 %0, %1 offset:" lit : "=v"(dst) : "v"(a) : "memory")
#define SHUF8(a, b) __builtin_shufflevector((a), (b), 0, 1, 2, 3, 4, 5, 6, 7)

typedef __attribute__((address_space(3))) unsigned int lds_u32;
typedef __attribute__((address_space(1))) const unsigned int glb_u32;

__device__ __forceinline__ void gload16(const __bf16* g, char* l) {
    __builtin_amdgcn_global_load_lds((glb_u32*)g, (lds_u32*)l, 16, 0, 0);
}

// problem sizes
static constexpr int BATCH = 4;
static constexpr int CH    = 256;
static constexpr int M_TOT = BATCH * 4096;  // 16384

// qkv softmax pre-scale folded into Q: 0.125 * log2(e)
static constexpr float QSCALE = 0.18033688011112042f;

// workspace layout (bytes, 16-aligned)
static constexpr size_t OFF_WQKV  = 0;                              // 196608 bf16
static constexpr size_t OFF_WOUT  = 196608ull * 2;                  // 65536 bf16
static constexpr size_t OFF_STATS = OFF_WOUT + 65536ull * 2;        // 128 float2
static constexpr size_t OFF_HID   = OFF_STATS + 1024;               // hid / attn_out bf16
static constexpr size_t OFF_Q     = OFF_HID + (size_t)M_TOT * CH * 2;
static constexpr size_t OFF_K     = OFF_Q   + (size_t)M_TOT * CH * 2;
static constexpr size_t OFF_V     = OFF_K   + (size_t)M_TOT * CH * 2;

// ---------------------------------------------------------------------------
// 1) fused: GN stats (blocks 0..127) + weight convert/permute (blocks 128..1151)
// ---------------------------------------------------------------------------
__global__ __launch_bounds__(256) void pre_kernel(const float* __restrict__ x,
                                                  float2* __restrict__ stats,
                                                  const float* __restrict__ wq,
                                                  const float* __restrict__ wo,
                                                  __bf16* __restrict__ wqf,
                                                  __bf16* __restrict__ wof) {
    if (blockIdx.x < 128) {
        int bg = blockIdx.x;  // 0..127
        const float4* p = (const float4*)(x + (size_t)bg * 32768);
        float s = 0.f, ss = 0.f;
        for (int i = threadIdx.x; i < 8192; i += 256) {
            float4 v = p[i];
            s  += (v.x + v.y) + (v.z + v.w);
            ss += v.x * v.x + v.y * v.y + v.z * v.z + v.w * v.w;
        }
#pragma unroll
        for (int d = 32; d > 0; d >>= 1) { s += __shfl_down(s, d); ss += __shfl_down(ss, d); }
        __shared__ float sh[8];
        int w = threadIdx.x >> 6, l = threadIdx.x & 63;
        if (l == 0) { sh[w] = s; sh[4 + w] = ss; }
        __syncthreads();
        if (threadIdx.x == 0) {
            float S = sh[0] + sh[1] + sh[2] + sh[3];
            float SS = sh[4] + sh[5] + sh[6] + sh[7];
            float mean = S * (1.f / 32768.f);
            float var  = SS * (1.f / 32768.f) - mean * mean;
            stats[bg] = make_float2(mean, rsqrtf(var + 1e-5f));
        }
    } else {
        int i = (blockIdx.x - 128) * 256 + threadIdx.x;   // 0 .. 262143
        if (i < 196608) {
            int e = i & 7, l = (i >> 3) & 63, kk = (i >> 9) & 7, jt = i >> 12;  // jt 0..47
            int kidx = kk * 32 + ((l >> 4) << 3) + e;
            int n = jt * 16 + (l & 15);
            wqf[i] = (__bf16)wq[kidx * 768 + n];
        } else {
            int i2 = i - 196608;                  // 0 .. 65535
            int e = i2 & 7, l = (i2 >> 3) & 63, kk = (i2 >> 9) & 7, jt = i2 >> 12;  // jt 0..15
            int kidx = kk * 32 + ((l >> 4) << 3) + e;
            int n = jt * 16 + (l & 15);
            wof[i2] = (__bf16)wo[kidx * 256 + n];
        }
    }
}

// ---------------------------------------------------------------------------
// 2) GN apply + transpose: hid[b][n][c] = gn(x)[b][c][n]  (bf16)
// ---------------------------------------------------------------------------
__global__ __launch_bounds__(256) void gn_apply(const float* __restrict__ x,
                                                const float* __restrict__ gamma,
                                                const float* __restrict__ beta,
                                                const float2* __restrict__ stats,
                                                __bf16* __restrict__ hid) {
    int b  = blockIdx.x >> 6;
    int n0 = (blockIdx.x & 63) << 6;
    int c  = threadIdx.x;
    float2 st = stats[b * 32 + (c >> 3)];
    float gm = gamma[c] * st.y;
    float bt = beta[c] - st.x * gm;
    const float* xp = x + ((size_t)(b * 256 + c)) * 4096 + n0;
    __bf16* hp = hid + ((size_t)(b * 4096 + n0)) * 256 + c;
#pragma unroll
    for (int j4 = 0; j4 < 16; ++j4) {
        float4 v = *(const float4*)(xp + j4 * 4);
        hp[(size_t)(j4 * 4 + 0) * 256] = (__bf16)(v.x * gm + bt);
        hp[(size_t)(j4 * 4 + 1) * 256] = (__bf16)(v.y * gm + bt);
        hp[(size_t)(j4 * 4 + 2) * 256] = (__bf16)(v.z * gm + bt);
        hp[(size_t)(j4 * 4 + 3) * 256] = (__bf16)(v.w * gm + bt);
    }
}

// ---------------------------------------------------------------------------
// 3) QKV GEMM: [16384,256] x [256,768] + bias -> q/k/v [B,H,4096,64] bf16
//    Q pre-scaled by 0.125*log2(e).
// ---------------------------------------------------------------------------
__global__ __launch_bounds__(256) void qkv_gemm(const __bf16* __restrict__ hid,
                                                const __bf16* __restrict__ wf,
                                                const float* __restrict__ bqkv,
                                                __bf16* __restrict__ qb,
                                                __bf16* __restrict__ kb,
                                                __bf16* __restrict__ vb) {
    const int mt = blockIdx.x, nt = blockIdx.y;
    const int tid = threadIdx.x;
    const int w = tid >> 6, l = tid & 63;
    const int lr = l & 15, lh = l >> 4;
    f32x4 acc[4] = {{0.f,0.f,0.f,0.f},{0.f,0.f,0.f,0.f},{0.f,0.f,0.f,0.f},{0.f,0.f,0.f,0.f}};
    const __bf16* ap = hid + (size_t)(mt * 64 + w * 16 + lr) * 256 + lh * 8;
#pragma unroll
    for (int kk = 0; kk < 8; ++kk) {
        bf16x8 a = *(const bf16x8*)(ap + kk * 32);
#pragma unroll
        for (int fj = 0; fj < 4; ++fj) {
            bf16x8 bf = *(const bf16x8*)(wf + (size_t)(((nt * 4 + fj) * 8 + kk) * 64 + l) * 8);
            acc[fj] = MFMA16(a, bf, acc[fj]);
        }
    }
    int mbase = mt * 64 + w * 16 + lh * 4;
#pragma unroll
    for (int fj = 0; fj < 4; ++fj) {
        int j = nt * 64 + fj * 16 + lr;
        int head = j / 192, rem = j % 192;
        int part = rem >> 6, dd = rem & 63;
        float bias = bqkv[j];
        float sc = (part == 0) ? QSCALE : 1.0f;
        __bf16* dst = (part == 0) ? qb : (part == 1) ? kb : vb;
#pragma unroll
        for (int r = 0; r < 4; ++r) {
            int m = mbase + r;
            int b = m >> 12, n = m & 4095;
            dst[((size_t)((b * 4 + head) * 4096 + n)) * 64 + dd] = (__bf16)((acc[fj][r] + bias) * sc);
        }
    }
}

// ---------------------------------------------------------------------------
// 4) Flash attention, swapped-operand, STATIC softmax, x32 PV.
//    128-row super-tile (2 q-subtiles/wave), grid 512, XCD swizzle.
//    TWO KV tiles per barrier phase (staggered): stage(t+2,t+3) -> QK(t0) ->
//    trr(t0) -> exp(t0) -> QK(t1) -> wait -> [trr(t1) | PV(t0) | exp(t1)] ->
//    wait -> PV(t1) -> barrier.  LDS 64KB: K slots[4] | V slots[4].
// ---------------------------------------------------------------------------
__global__ __launch_bounds__(256, 2) void attn_fwd(const __bf16* __restrict__ q,
                                                   const __bf16* __restrict__ k,
                                                   const __bf16* __restrict__ v,
                                                   __bf16* __restrict__ ao) {
    const int id = blockIdx.x;
    const int within = id >> 3;                       // 0..63
    const int bh = ((id & 7) << 1) + (within >> 5);   // XCD (id&7) owns bh pair
    const int q0 = (within & 31) * 128;
    const int tid = threadIdx.x;
    const int wv = tid >> 6, l = tid & 63;
    const int lr = l & 15, lh = l >> 4;

    __shared__ __attribute__((aligned(16))) char smem[65536];  // K[4][8K] | V[4][8K]

    const size_t base = (size_t)bh * (4096 * 64);

    // ---- staging addresses (chunk c = wv*64 + l, and +256) ----
    const int c0 = wv * 64 + l;
    const int rK = c0 >> 3, cbK = l & 7;
    const int gk0 = rK * 64 + (cbK ^ (rK & 7)) * 8;        // elements
    const int gk1 = gk0 + 2048;                             // +32 rows
    // V (pi-keyed layout): c -> dt=c>>7, kq=(c>>3)&15, klo=(l>>1)&3, d8=l&1
    const int dt0 = c0 >> 7, kq0 = (c0 >> 3) & 15, klo0 = (l >> 1) & 3, d80 = l & 1;
    const int gv0 = (kq0 * 4 + klo0) * 64 + dt0 * 16 + d80 * 8;
    const int gv1 = gv0 + 32;                               // dt+2
    const int lw0 = wv * 1024;                              // wave-uniform LDS bases
    const int lw1 = 4096 + wv * 1024;

    const __bf16* kg = k + base;
    const __bf16* vg = v + base;

    // per-lane tr-read base for V slot 0
    const unsigned lanep = (unsigned)(lr * 2 + lh * 128);
    const unsigned vAbase = (unsigned)(size_t)(smem + 32768) + lanep;

    // Q fragments for both subtiles (B-operand of swapped QK^T; pre-scaled)
    bf16x8 qf0a, qf1a, qf0b, qf1b;
    {
        const __bf16* qp = q + base + (size_t)(q0 + wv * 16 + lr) * 64 + lh * 8;
        qf0a = *(const bf16x8*)qp;
        qf1a = *(const bf16x8*)(qp + 32);
        qf0b = *(const bf16x8*)(qp + 4096);        // +64 rows
        qf1b = *(const bf16x8*)(qp + 4096 + 32);
    }
    bf16x8 ones;
#pragma unroll
    for (int e = 0; e < 8; ++e) ones[e] = (__bf16)1.0f;

    f32x4 oa[4] = {{0.f,0.f,0.f,0.f},{0.f,0.f,0.f,0.f},{0.f,0.f,0.f,0.f},{0.f,0.f,0.f,0.f}};
    f32x4 ob[4] = {{0.f,0.f,0.f,0.f},{0.f,0.f,0.f,0.f},{0.f,0.f,0.f,0.f},{0.f,0.f,0.f,0.f}};
    f32x4 o4a = {0.f, 0.f, 0.f, 0.f};
    f32x4 o4b = {0.f, 0.f, 0.f, 0.f};

    // helper: QK^T for one tile (both q-subtiles share the K fragments)
    auto qk = [&](const char* Kc, f32x4* sa, f32x4* sb) {
        const f32x4 z = {0.f, 0.f, 0.f, 0.f};
        __builtin_amdgcn_s_setprio(1);
#pragma unroll
        for (int fj = 0; fj < 4; ++fj) {
            int row = fj * 16 + lr;
            bf16x8 kb0 = *(const bf16x8*)(Kc + row * 128 + ((lh * 16) ^ ((row & 7) << 4)));
            bf16x8 kb1 = *(const bf16x8*)(Kc + row * 128 + (((4 + lh) * 16) ^ ((row & 7) << 4)));
            sa[fj] = MFMA16(kb0, qf0a, z);
            sb[fj] = MFMA16(kb0, qf0b, z);
            sa[fj] = MFMA16(kb1, qf1a, sa[fj]);
            sb[fj] = MFMA16(kb1, qf1b, sb[fj]);
        }
        __builtin_amdgcn_s_setprio(0);
    };
    // helper: exp2 + pack both subtiles
    auto expPack = [&](const f32x4* sa, const f32x4* sb,
                       bf16x8& Ba0, bf16x8& Ba1, bf16x8& Bb0, bf16x8& Bb1) {
#pragma unroll
        for (int fj = 0; fj < 4; ++fj)
#pragma unroll
            for (int r = 0; r < 4; ++r) {
                float pa = __builtin_amdgcn_exp2f(sa[fj][r]);
                float pb = __builtin_amdgcn_exp2f(sb[fj][r]);
                if (fj < 2) { Ba0[fj * 4 + r] = (__bf16)pa; Bb0[fj * 4 + r] = (__bf16)pb; }
                else        { Ba1[(fj - 2) * 4 + r] = (__bf16)pa; Bb1[(fj - 2) * 4 + r] = (__bf16)pb; }
            }
    };
    // helper: PV cluster for one tile
    auto pv = [&](const bf16x4* u, bf16x8 Ba0, bf16x8 Ba1, bf16x8 Bb0, bf16x8 Bb1) {
        __builtin_amdgcn_s_setprio(1);
        bf16x8 v01 = SHUF8(u[0],  u[1]),  v23 = SHUF8(u[2],  u[3]);
        bf16x8 v45 = SHUF8(u[4],  u[5]),  v67 = SHUF8(u[6],  u[7]);
        oa[0] = MFMA16(v01, Ba0, oa[0]);  ob[0] = MFMA16(v01, Bb0, ob[0]);
        oa[1] = MFMA16(v45, Ba0, oa[1]);  ob[1] = MFMA16(v45, Bb0, ob[1]);
        oa[0] = MFMA16(v23, Ba1, oa[0]);  ob[0] = MFMA16(v23, Bb1, ob[0]);
        oa[1] = MFMA16(v67, Ba1, oa[1]);  ob[1] = MFMA16(v67, Bb1, ob[1]);
        o4a   = MFMA16(ones, Ba0, o4a);   o4b   = MFMA16(ones, Bb0, o4b);
        bf16x8 v89 = SHUF8(u[8],  u[9]),  vab = SHUF8(u[10], u[11]);
        bf16x8 vcd = SHUF8(u[12], u[13]), vef = SHUF8(u[14], u[15]);
        oa[2] = MFMA16(v89, Ba0, oa[2]);  ob[2] = MFMA16(v89, Bb0, ob[2]);
        oa[3] = MFMA16(vcd, Ba0, oa[3]);  ob[3] = MFMA16(vcd, Bb0, ob[3]);
        oa[2] = MFMA16(vab, Ba1, oa[2]);  ob[2] = MFMA16(vab, Bb1, ob[2]);
        oa[3] = MFMA16(vef, Ba1, oa[3]);  ob[3] = MFMA16(vef, Bb1, ob[3]);
        o4a   = MFMA16(ones, Ba1, o4a);   o4b   = MFMA16(ones, Bb1, o4b);
        __builtin_amdgcn_s_setprio(0);
    };

    // prologue: stage tiles 0,1 into pair 0
    gload16(kg + gk0, smem + lw0);
    gload16(kg + gk1, smem + lw1);
    gload16(kg + 4096 + gk0, smem + 8192 + lw0);
    gload16(kg + 4096 + gk1, smem + 8192 + lw1);
    gload16(vg + gv0, smem + 32768 + lw0);
    gload16(vg + gv1, smem + 32768 + lw1);
    gload16(vg + 4096 + gv0, smem + 32768 + 8192 + lw0);
    gload16(vg + 4096 + gv1, smem + 32768 + 8192 + lw1);
    __syncthreads();

    auto phase = [&](unsigned pb, int tnext) {   // pb = pair byte offset (0 or 16384)
        // stage next pair into the other slots
        if (tnext < 64) {
            const __bf16* kp = kg + (size_t)tnext * 4096;
            const __bf16* vp = vg + (size_t)tnext * 4096;
            char* kd = smem + (pb ^ 16384u);
            char* vd = smem + 32768 + (pb ^ 16384u);
            gload16(kp + gk0, kd + lw0);
            gload16(kp + gk1, kd + lw1);
            gload16(kp + 4096 + gk0, kd + 8192 + lw0);
            gload16(kp + 4096 + gk1, kd + 8192 + lw1);
            gload16(vp + gv0, vd + lw0);
            gload16(vp + gv1, vd + lw1);
            gload16(vp + 4096 + gv0, vd + 8192 + lw0);
            gload16(vp + 4096 + gv1, vd + 8192 + lw1);
        }
        const char* Kc = smem + pb;
        const unsigned vA = vAbase + pb;

        // ---- tile 0: QK, tr-reads, exp ----
        f32x4 sa0[4], sb0[4];
        qk(Kc, sa0, sb0);
        bf16x4 u[16];
        TRRM(u[0],  vA, "0");    TRR(u[1],  vA, "512");
        TRR(u[2],  vA, "1024");  TRR(u[3],  vA, "1536");
        TRR(u[4],  vA, "2048");  TRR(u[5],  vA, "2560");
        TRR(u[6],  vA, "3072");  TRR(u[7],  vA, "3584");
        TRR(u[8],  vA, "4096");  TRR(u[9],  vA, "4608");
        TRR(u[10], vA, "5120");  TRR(u[11], vA, "5632");
        TRR(u[12], vA, "6144");  TRR(u[13], vA, "6656");
        TRR(u[14], vA, "7168");  TRR(u[15], vA, "7680");
        bf16x8 Ba0, Ba1, Bb0, Bb1;
        expPack(sa0, sb0, Ba0, Ba1, Bb0, Bb1);

        // ---- tile 1: QK (independent MFMA stream) ----
        f32x4 sa1[4], sb1[4];
        qk(Kc + 8192, sa1, sb1);

        // ---- wait for trr(t0) [+ QK(t1) ds reads]; then mixed region ----
        asm volatile("s_waitcnt lgkmcnt(0)" ::: "memory");
        __builtin_amdgcn_sched_barrier(0);
        bf16x4 w[16];
        const unsigned vA1 = vA + 8192u;
        TRRM(w[0],  vA1, "0");    TRR(w[1],  vA1, "512");
        TRR(w[2],  vA1, "1024");  TRR(w[3],  vA1, "1536");
        TRR(w[4],  vA1, "2048");  TRR(w[5],  vA1, "2560");
        TRR(w[6],  vA1, "3072");  TRR(w[7],  vA1, "3584");
        TRR(w[8],  vA1, "4096");  TRR(w[9],  vA1, "4608");
        TRR(w[10], vA1, "5120");  TRR(w[11], vA1, "5632");
        TRR(w[12], vA1, "6144");  TRR(w[13], vA1, "6656");
        TRR(w[14], vA1, "7168");  TRR(w[15], vA1, "7680");
        pv(u, Ba0, Ba1, Bb0, Bb1);              // MFMA cluster (t0)
        bf16x8 Ca0, Ca1, Cb0, Cb1;
        expPack(sa1, sb1, Ca0, Ca1, Cb0, Cb1);  // VALU (t1) — interleaves with PV(t0)

        asm volatile("s_waitcnt lgkmcnt(0)" ::: "memory");
        __builtin_amdgcn_sched_barrier(0);
        pv(w, Ca0, Ca1, Cb0, Cb1);              // MFMA cluster (t1)

        __syncthreads();   // implicit vmcnt(0): next pair staged; flip safe
    };

    for (int t = 0; t < 64; t += 4) {
        phase(0u,      t + 2);
        phase(16384u,  t + 4);
    }

    // epilogue: every lane holds the full denominators in o4a[0]/o4b[0]
    float inva = 1.0f / o4a[0];
    float invb = 1.0f / o4b[0];
    int b = bh >> 2, h = bh & 3;
    int n = q0 + wv * 16 + lr;
    __bf16* dsta = ao + ((size_t)(b * 4096 + n)) * 256 + h * 64 + lh * 4;
    __bf16* dstb = dsta + 64 * 256;
#pragma unroll
    for (int fd = 0; fd < 4; ++fd) {
        bf16x4 pka, pkb;
#pragma unroll
        for (int r = 0; r < 4; ++r) {
            pka[r] = (__bf16)(oa[fd][r] * inva);
            pkb[r] = (__bf16)(ob[fd][r] * invb);
        }
        *(bf16x4*)(dsta + fd * 16) = pka;
        *(bf16x4*)(dstb + fd * 16) = pkb;
    }
}

// ---------------------------------------------------------------------------
// 5) out projection + bias + residual + 1/sqrt(2), transposed store [B,C,N]
// ---------------------------------------------------------------------------
__global__ __launch_bounds__(256) void out_gemm(const __bf16* __restrict__ ao,
                                                const __bf16* __restrict__ wf,
                                                const float* __restrict__ bout,
                                                const float* __restrict__ x,
                                                float* __restrict__ out) {
    const int mt = blockIdx.x, nt = blockIdx.y;
    const int tid = threadIdx.x;
    const int w = tid >> 6, l = tid & 63;
    const int lr = l & 15, lh = l >> 4;
    f32x4 acc[4] = {{0.f,0.f,0.f,0.f},{0.f,0.f,0.f,0.f},{0.f,0.f,0.f,0.f},{0.f,0.f,0.f,0.f}};
    const __bf16* ap = ao + (size_t)(mt * 64 + w * 16 + lr) * 256 + lh * 8;
#pragma unroll
    for (int kk = 0; kk < 8; ++kk) {
        bf16x8 a = *(const bf16x8*)(ap + kk * 32);
#pragma unroll
        for (int fj = 0; fj < 4; ++fj) {
            bf16x8 bf = *(const bf16x8*)(wf + (size_t)(((nt * 4 + fj) * 8 + kk) * 64 + l) * 8);
            acc[fj] = MFMA16(a, bf, acc[fj]);
        }
    }
    __shared__ float tile[64][72];
#pragma unroll
    for (int fj = 0; fj < 4; ++fj) {
        float bias = bout[nt * 64 + fj * 16 + lr];
#pragma unroll
        for (int r = 0; r < 4; ++r)
            tile[w * 16 + lh * 4 + r][fj * 16 + lr] = acc[fj][r] + bias;
    }
    __syncthreads();
    int b  = mt >> 6;
    int n0 = (mt & 63) * 64;
    int c0 = nt * 64;
    int cl = tid >> 2, nq = tid & 3;
    size_t gbase = ((size_t)(b * 256 + c0 + cl)) * 4096 + n0 + nq * 16;
#pragma unroll
    for (int i = 0; i < 16; i += 4) {
        float4 xv = *(const float4*)(x + gbase + i);
        float4 ov;
        ov.x = (tile[nq * 16 + i + 0][cl] + xv.x) * 0.70710678118654752f;
        ov.y = (tile[nq * 16 + i + 1][cl] + xv.y) * 0.70710678118654752f;
        ov.z = (tile[nq * 16 + i + 2][cl] + xv.z) * 0.70710678118654752f;
        ov.w = (tile[nq * 16 + i + 3][cl] + xv.w) * 0.70710678118654752f;
        *(float4*)(out + gbase + i) = ov;
    }
}

// ---------------------------------------------------------------------------
extern "C" void kernel_launch(void* const* d_in, const int* in_sizes, int n_in,
                              void* d_out, int out_size, void* d_ws, size_t ws_size,
                              hipStream_t stream) {
    const float* x     = (const float*)d_in[0];
    const float* gamma = (const float*)d_in[1];
    const float* beta  = (const float*)d_in[2];
    const float* W_qkv = (const float*)d_in[3];
    const float* b_qkv = (const float*)d_in[4];
    const float* W_out = (const float*)d_in[5];
    const float* b_out = (const float*)d_in[6];
    float* out = (float*)d_out;
    char* ws = (char*)d_ws;

    __bf16* wqf   = (__bf16*)(ws + OFF_WQKV);
    __bf16* wof   = (__bf16*)(ws + OFF_WOUT);
    float2* stats = (float2*)(ws + OFF_STATS);
    __bf16* hid   = (__bf16*)(ws + OFF_HID);   // hid, then attn_out
    __bf16* qb    = (__bf16*)(ws + OFF_Q);
    __bf16* kb    = (__bf16*)(ws + OFF_K);
    __bf16* vb    = (__bf16*)(ws + OFF_V);

    pre_kernel<<<1152, 256, 0, stream>>>(x, stats, W_qkv, W_out, wqf, wof);
    gn_apply<<<256, 256, 0, stream>>>(x, gamma, beta, stats, hid);
    qkv_gemm<<<dim3(256, 12), 256, 0, stream>>>(hid, wqf, b_qkv, qb, kb, vb);
    attn_fwd<<<512, 256, 0, stream>>>(qb, kb, vb, hid);
    out_gemm<<<dim3(256, 4), 256, 0, stream>>>(hid, wof, b_out, x, out);
}